// Round 16
// baseline (472.518 us; speedup 1.0000x reference)
//
#include <hip/hip_runtime.h>
#include <hip/hip_bf16.h>

// ---------------------------------------------------------------------------
// Fused self-attention, B=8 N=4096 D=256, f32 in/out, bf16 MFMA internally.
// ws: Qs bf16 [B*N][256] @0       (pre-scaled by log2e/16)
//     Kb bf16 [B*N][256] @16MB
//     VT bf16 [B][256][N] @32MB   (columns permuted per 16-block: 4-7 <-> 8-11)
// R16: BARRIER-FREE attention. Each wave owns a private 32KB KVB=32 tile for
// a disjoint kv-quarter, stages it itself, syncs only via wave-local
// vmcnt/lgkmcnt, reads fragments into registers (kreg/vreg) before the next
// stage overwrites. 4-way in-block LDS merge at the end (2 barriers total).
// ---------------------------------------------------------------------------

typedef __attribute__((ext_vector_type(8))) short short8;    // 8 bf16
typedef __attribute__((ext_vector_type(4))) float f32x4;
typedef __attribute__((ext_vector_type(16))) float f32x16;
typedef __attribute__((ext_vector_type(2))) unsigned uint2v;

#define MFMA16(A, B, C) __builtin_amdgcn_mfma_f32_16x16x32_bf16(A, B, C, 0, 0, 0)
#define MFMA32(A, B, C) __builtin_amdgcn_mfma_f32_32x32x16_bf16(A, B, C, 0, 0, 0)

__device__ __forceinline__ unsigned short f2bf(float f) {
  union { float f; unsigned u; } v; v.f = f;
  unsigned r = v.u + 0x7FFFu + ((v.u >> 16) & 1u);   // RNE
  return (unsigned short)(r >> 16);
}

__device__ __forceinline__ ushort4 pack4(float4 v) {
  ushort4 r;
  r.x = f2bf(v.x); r.y = f2bf(v.y); r.z = f2bf(v.z); r.w = f2bf(v.w);
  return r;
}

__device__ __forceinline__ unsigned packbf2(float a, float b) {
  union { __hip_bfloat162 b2; unsigned u; } cv;
  cv.b2 = __float22bfloat162_rn(make_float2(a, b));
  return cv.u;
}

__device__ __forceinline__ void gload_lds16(const void* g, void* l) {
  __builtin_amdgcn_global_load_lds(
      (const __attribute__((address_space(1))) void*)g,
      (__attribute__((address_space(3))) void*)l, 16, 0, 0);
}

// cross-half (lane <-> lane^32) reduce on the VALU (R15-verified).
__device__ __forceinline__ float xhalf_max(float x) {
  uint2v r = __builtin_amdgcn_permlane32_swap(
      __float_as_uint(x), __float_as_uint(x), false, false);
  return fmaxf(__uint_as_float(r.x), __uint_as_float(r.y));
}
__device__ __forceinline__ float xhalf_sum(float x) {
  uint2v r = __builtin_amdgcn_permlane32_swap(
      __float_as_uint(x), __float_as_uint(x), false, false);
  return __uint_as_float(r.x) + __uint_as_float(r.y);
}

// --------------------------- Projection GEMM (R3/R4-verified) -------------
template <int MODE>
__global__ __launch_bounds__(256)
void proj_kernel(const float* __restrict__ A, const float* __restrict__ Bm,
                 const float* __restrict__ bias,
                 unsigned short* __restrict__ Qs, unsigned short* __restrict__ Kb,
                 unsigned short* __restrict__ VT) {
  __shared__ __align__(16) unsigned short as_[2][128 * 64];
  __shared__ __align__(16) unsigned short bs_[2][128 * 64];

  const int tid = threadIdx.x;
  const int wid = tid >> 6, lane = tid & 63, l15 = lane & 15, lhi = lane >> 4;
  int m0, n0;
  if (MODE == 0) { m0 = blockIdx.y * 128; n0 = blockIdx.x * 128; }
  else           { m0 = blockIdx.x * 128; n0 = blockIdx.y * 128; }
  const float* Arow = A + (size_t)m0 * 256;
  const float* Brow = Bm + (size_t)n0 * 256;

  const int srow = tid >> 4;
  const int c4 = tid & 15;
  float4 ra[8], rb[8];

  auto loadslice = [&](int kc) {
#pragma unroll
    for (int i = 0; i < 8; ++i) {
      int row = i * 16 + srow;
      ra[i] = *(const float4*)(Arow + (size_t)row * 256 + kc * 64 + c4 * 4);
      rb[i] = *(const float4*)(Brow + (size_t)row * 256 + kc * 64 + c4 * 4);
    }
  };
  auto writeslice = [&](int buf) {
#pragma unroll
    for (int i = 0; i < 8; ++i) {
      int row = i * 16 + srow;
      int g = c4 >> 1, half = c4 & 1;
      int off = row * 64 + ((g ^ (row & 7)) << 3) + half * 4;
      *(ushort4*)&as_[buf][off] = pack4(ra[i]);
      *(ushort4*)&bs_[buf][off] = pack4(rb[i]);
    }
  };

  f32x4 acc[2][8];
#pragma unroll
  for (int mt = 0; mt < 2; ++mt)
#pragma unroll
    for (int nt = 0; nt < 8; ++nt) acc[mt][nt] = (f32x4){0.f, 0.f, 0.f, 0.f};

  loadslice(0);
  writeslice(0);
  int cur = 0;
  for (int kc = 0; kc < 4; ++kc) {
    __syncthreads();
    if (kc < 3) loadslice(kc + 1);
#pragma unroll
    for (int ks = 0; ks < 2; ++ks) {
      short8 af[2];
#pragma unroll
      for (int mt = 0; mt < 2; ++mt) {
        int row = wid * 32 + mt * 16 + l15;
        int g = ks * 4 + lhi;
        af[mt] = *(const short8*)&as_[cur][row * 64 + ((g ^ (row & 7)) << 3)];
      }
#pragma unroll
      for (int nt = 0; nt < 8; ++nt) {
        int row = nt * 16 + l15;
        int g = ks * 4 + lhi;
        short8 bf = *(const short8*)&bs_[cur][row * 64 + ((g ^ (row & 7)) << 3)];
        acc[0][nt] = MFMA16(af[0], bf, acc[0][nt]);
        acc[1][nt] = MFMA16(af[1], bf, acc[1][nt]);
      }
    }
    if (kc < 3) writeslice(cur ^ 1);
    cur ^= 1;
  }

  const float QSC = 0.0901684400555602f;  // log2(e)/16
#pragma unroll
  for (int nt = 0; nt < 8; ++nt) {
    if (MODE == 0) {
      int e = n0 + nt * 16 + l15;
      float bv = bias[e];
#pragma unroll
      for (int mt = 0; mt < 2; ++mt)
#pragma unroll
        for (int r = 0; r < 4; ++r) {
          int tok = m0 + wid * 32 + mt * 16 + lhi * 4 + r;
          float val = acc[mt][nt][r] + bv;
          if (e < 256) Qs[(size_t)tok * 256 + e] = f2bf(val * QSC);
          else         Kb[(size_t)tok * 256 + (e - 256)] = f2bf(val);
        }
    } else {
      int tok = n0 + nt * 16 + l15;
      int bb = tok >> 12, n = tok & 4095;
      int t4 = n & 15;
      int flip = ((t4 >> 2) ^ (t4 >> 3)) & 1;
      int n2 = (n & ~15) | (t4 ^ (flip ? 12 : 0));
#pragma unroll
      for (int mt = 0; mt < 2; ++mt)
#pragma unroll
        for (int r = 0; r < 4; ++r) {
          int d = m0 + wid * 32 + mt * 16 + lhi * 4 + r;
          float val = acc[mt][nt][r] + bias[512 + d];
          VT[(size_t)bb * (256 * 4096) + (size_t)d * 4096 + n2] = f2bf(val);
        }
    }
  }
}

// --------------------------- Flash attention, barrier-free ----------------
// Grid 1024 = 8 batch * 128 q-blocks; 256 threads = 4 waves, ALL on the same
// 32 q rows; wave w owns kv-quarter w*1024..+1024 (32 iters of KVB=32) with a
// PRIVATE 32KB LDS tile (128KB total -> 1 block/CU). No __syncthreads in the
// main loop: wave-local vmcnt/lgkmcnt only. 4-way in-block merge at the end.
__global__ __launch_bounds__(256, 1)
void attn_kernel(const unsigned short* __restrict__ Qs,
                 const unsigned short* __restrict__ Kb,
                 const unsigned short* __restrict__ VT,
                 float* __restrict__ out) {
  __shared__ __align__(16) unsigned short lds_kv[4][16384];  // per-wave K|V, 128KB
  __shared__ float2 mlb[4][32];                              // 1KB

  const int tid = threadIdx.x;
  const int wid = tid >> 6, lane = tid & 63, l31 = lane & 31, h = lane >> 5;
  const int blk = blockIdx.x;
  const int b = blk & 7;                 // batch -> XCD pin
  const int qblk = blk >> 3;             // 0..127
  const int q0 = qblk * 32;

  // Q B-frags: lane holds q = l31, k = ks*16 + h*8 + j (same for all waves)
  const unsigned short* qp = Qs + ((size_t)b * 4096 + q0 + l31) * 256 + h * 8;
  short8 qf[16];
#pragma unroll
  for (int ks = 0; ks < 16; ++ks) qf[ks] = *(const short8*)(qp + ks * 16);

  f32x16 acco[8];
#pragma unroll
  for (int dt = 0; dt < 8; ++dt)
#pragma unroll
    for (int j = 0; j < 16; ++j) acco[dt][j] = 0.f;
  float m = -1e30f, lsum = 0.f;

  const unsigned short* kbase = Kb + (size_t)b * 4096 * 256;
  const unsigned short* vtb   = VT + (size_t)b * 256 * 4096;
  unsigned short* kbuf = &lds_kv[wid][0];      // 16KB: K[32][256] swizzled
  unsigned short* vbuf = &lds_kv[wid][8192];   // 16KB: VT[256][32] swizzled

  // wave stages its own tile: 2048 granules of 16B over 64 lanes = 32/lane
  auto stage = [&](int it) {
    const int kv0 = wid * 1024 + it * 32;
    const unsigned short* ksrc = kbase + (size_t)kv0 * 256;
#pragma unroll
    for (int i = 0; i < 16; ++i) {
      int g = i * 64 + lane;                // K granule (32 rows x 32)
      int row = g >> 5, cp = g & 31;
      int sg = (row << 5) | (cp ^ (row & 7));
      gload_lds16(ksrc + sg * 8, kbuf + (size_t)(i * 64) * 8);
    }
#pragma unroll
    for (int i = 0; i < 16; ++i) {
      int g = i * 64 + lane;                // V granule (256 d x 4)
      int d = g >> 2, cp = g & 3;
      int sc = cp ^ ((d >> 1) & 3);         // sigma(d)=(d>>1)&3
      gload_lds16(vtb + (size_t)d * 4096 + kv0 + sc * 8,
                  vbuf + (size_t)(i * 64) * 8);
    }
  };

  stage(0);
  for (int it = 0; it < 32; ++it) {
    // own stage loads complete -> tile readable (wave-local, no barrier)
    asm volatile("s_waitcnt vmcnt(0)" ::: "memory");
    __builtin_amdgcn_sched_barrier(0);

    // fragments -> registers (frees the buffer for the next stage)
    short8 kreg[16];
#pragma unroll
    for (int ks = 0; ks < 16; ++ks)
      kreg[ks] =
          *(const short8*)&kbuf[l31 * 256 + (((2 * ks + h) ^ (l31 & 7)) << 3)];
    short8 vreg[2][8];
#pragma unroll
    for (int kt = 0; kt < 2; ++kt)
#pragma unroll
      for (int dt = 0; dt < 8; ++dt) {
        const int d = dt * 32 + l31;
        vreg[kt][dt] = *(const short8*)
            &vbuf[d * 32 + (((2 * kt + h) ^ ((l31 >> 1) & 3)) << 3)];
      }

    // ---- S^T = K·Q^T (compiler interleaves lgkmcnt with reads) ----
    f32x16 s0;
#pragma unroll
    for (int j = 0; j < 16; ++j) s0[j] = 0.f;
    __builtin_amdgcn_s_setprio(1);
#pragma unroll
    for (int ks = 0; ks < 16; ++ks) s0 = MFMA32(kreg[ks], qf[ks], s0);
    __builtin_amdgcn_s_setprio(0);

    // all ds_reads done -> safe to overwrite tile; stage overlaps softmax+PV
    asm volatile("s_waitcnt lgkmcnt(0)" ::: "memory");
    __builtin_amdgcn_sched_barrier(0);
    if (it < 31) stage(it + 1);

    // ---- in-register online softmax for q = l31 ----
    float mx = s0[0];
#pragma unroll
    for (int r = 1; r < 16; ++r) mx = fmaxf(mx, s0[r]);
    mx = xhalf_max(mx);
    const float mo = m;
    const float mn = (mx > mo + 4.f) ? mx : mo;   // defer-max THR=4
    const float al = __builtin_amdgcn_exp2f(mo - mn);
    m = mn;
    if (__any(mn != mo)) {
      float alq[16];
#pragma unroll
      for (int r = 0; r < 16; ++r)
        alq[r] = __shfl(al, (r & 3) + 8 * (r >> 2) + 4 * h, 64);
#pragma unroll
      for (int dt = 0; dt < 8; ++dt)
#pragma unroll
        for (int r = 0; r < 16; ++r) acco[dt][r] *= alq[r];
    }

    // ---- P = exp2(S - mn); pack native; PV from vreg (reg-only) ----
#pragma unroll
    for (int r = 0; r < 8; ++r) s0[r] = __builtin_amdgcn_exp2f(s0[r] - mn);
    short8 pf0;
    {
      union { unsigned u[4]; short8 v; } a0;
#pragma unroll
      for (int k2 = 0; k2 < 4; ++k2)
        a0.u[k2] = packbf2(s0[2 * k2], s0[2 * k2 + 1]);
      pf0 = a0.v;
    }
    __builtin_amdgcn_s_setprio(1);
#pragma unroll
    for (int dt = 0; dt < 8; ++dt) acco[dt] = MFMA32(pf0, vreg[0][dt], acco[dt]);
    __builtin_amdgcn_s_setprio(0);
#pragma unroll
    for (int r = 8; r < 16; ++r) s0[r] = __builtin_amdgcn_exp2f(s0[r] - mn);
    short8 pf1;
    {
      union { unsigned u[4]; short8 v; } a1;
#pragma unroll
      for (int k2 = 0; k2 < 4; ++k2)
        a1.u[k2] = packbf2(s0[8 + 2 * k2], s0[9 + 2 * k2]);
      pf1 = a1.v;
    }
    __builtin_amdgcn_s_setprio(1);
#pragma unroll
    for (int dt = 0; dt < 8; ++dt) acco[dt] = MFMA32(pf1, vreg[1][dt], acco[dt]);
    __builtin_amdgcn_s_setprio(0);

    float rs = 0.f;
#pragma unroll
    for (int r = 0; r < 16; ++r) rs += s0[r];
    rs = xhalf_sum(rs);
    lsum = lsum * al + rs;
  }

  // ---- 4-way in-block merge (R7 pattern extended) ----
  __syncthreads();                       // everyone done with tiles
  float* fbuf = (float*)&lds_kv[0][0];   // 3 x 32KB partials (waves 1..3)
  if (wid > 0) {
    float* mb = fbuf + (size_t)(wid - 1) * 8192;
#pragma unroll
    for (int dt = 0; dt < 8; ++dt)
#pragma unroll
      for (int r = 0; r < 16; ++r) {
        int qp2 = (r & 3) + 8 * (r >> 2) + 4 * h;
        mb[qp2 * 256 + dt * 32 + l31] = acco[dt][r];
      }
  }
  if (lane < 32) mlb[wid][lane] = make_float2(m, lsum);
  __syncthreads();
  if (wid == 0) {
    float* orow = out + ((size_t)b * 4096 + q0) * 256;
#pragma unroll
    for (int r = 0; r < 16; ++r) {
      int qp2 = (r & 3) + 8 * (r >> 2) + 4 * h;
      float2 s1 = mlb[0][qp2], s2 = mlb[1][qp2];
      float2 s3 = mlb[2][qp2], s4 = mlb[3][qp2];
      float mM = fmaxf(fmaxf(s1.x, s2.x), fmaxf(s3.x, s4.x));
      float w1 = __builtin_amdgcn_exp2f(s1.x - mM);
      float w2 = __builtin_amdgcn_exp2f(s2.x - mM);
      float w3 = __builtin_amdgcn_exp2f(s3.x - mM);
      float w4 = __builtin_amdgcn_exp2f(s4.x - mM);
      float inv = 1.f / (w1 * s1.y + w2 * s2.y + w3 * s3.y + w4 * s4.y);
#pragma unroll
      for (int dt = 0; dt < 8; ++dt) {
        int off = qp2 * 256 + dt * 32 + l31;
        float v = acco[dt][r] * w1 + fbuf[off] * w2 +
                  fbuf[8192 + off] * w3 + fbuf[16384 + off] * w4;
        orow[off] = v * inv;
      }
    }
  }
}

// ---------------------------------------------------------------------------
extern "C" void kernel_launch(void* const* d_in, const int* in_sizes, int n_in,
                              void* d_out, int out_size, void* d_ws, size_t ws_size,
                              hipStream_t stream) {
  const float* x    = (const float*)d_in[0];   // [8,4096,256]
  const float* W    = (const float*)d_in[1];   // [768,256]
  const float* bias = (const float*)d_in[2];   // [768]
  float* out = (float*)d_out;                  // [8,4096,256] f32

  char* ws = (char*)d_ws;
  unsigned short* Qs = (unsigned short*)(ws);
  unsigned short* Kb = (unsigned short*)(ws + (size_t)16 * 1024 * 1024);
  unsigned short* VT = (unsigned short*)(ws + (size_t)32 * 1024 * 1024);

  proj_kernel<0><<<dim3(4, 256), 256, 0, stream>>>(x, W, bias, Qs, Kb, VT);
  proj_kernel<1><<<dim3(2, 256), 256, 0, stream>>>(W + 512 * 256, x, bias, Qs, Kb, VT);
  attn_kernel<<<1024, 256, 0, stream>>>(Qs, Kb, VT, out);
}